// Round 1
// baseline (116.934 us; speedup 1.0000x reference)
//
#include <hip/hip_runtime.h>
#include <math.h>

// Problem constants (fixed-size problem: B = 4194304)
#define BTOT 4194304
#define TPB  256
#define EPT  16                 // elements per thread
#define CS   (TPB * EPT)        // 4096 elements per chunk
#define NCH  (BTOT / CS)        // 1024 chunks
#define CPT  (NCH / TPB)        // 4 chunks per thread in K2

// ws layout (floats):
//   [0*NCH..)  Pv   chunk decay product (v-target recurrence)
//   [1*NCH..)  Sv   chunk local value at chunk start (zero carry)
//   [2*NCH..)  Pa   chunk decay product (advantage recurrence)
//   [3*NCH..)  Sa   chunk local value
//   [4*NCH..)  sL   sum of chunk-local A
//   [5*NCH..)  sq   sum of suffix decay products q
//   [6*NCH..)  sL2  sum L^2
//   [7*NCH..)  sLq  sum L*q
//   [8*NCH..)  sq2  sum q^2
//   [9*NCH..)  carry_v  (carry INTO chunk i, written by K2)
//   [10*NCH..) carry_a
//   [11*NCH]   mean,  [11*NCH+1] inv_std

__constant__ const float kG  = 0.99f;
__constant__ const float kGT = 0.99f * 0.95f;

__device__ __forceinline__ float wave_red(float x) {
#pragma unroll
    for (int o = 32; o > 0; o >>= 1) x += __shfl_down(x, o);
    return x;
}

__global__ __launch_bounds__(TPB) void k1_summarize(
    const float* __restrict__ r, const float* __restrict__ v,
    const int* __restrict__ mk, float* __restrict__ ws) {
    const int c = blockIdx.x;
    const int j = threadIdx.x;
    const int base = c * CS + j * EPT;

    float rr[EPT], vv[EPT + 1], dd[EPT];
    int mm[EPT];
    const float4* r4 = (const float4*)(r + base);
    const float4* v4 = (const float4*)(v + base);
    const int4*   m4 = (const int4*)(mk + base);
#pragma unroll
    for (int k = 0; k < EPT / 4; ++k) {
        float4 a = r4[k];
        rr[4*k] = a.x; rr[4*k+1] = a.y; rr[4*k+2] = a.z; rr[4*k+3] = a.w;
        float4 b = v4[k];
        vv[4*k] = b.x; vv[4*k+1] = b.y; vv[4*k+2] = b.z; vv[4*k+3] = b.w;
        int4 m = m4[k];
        mm[4*k] = m.x; mm[4*k+1] = m.y; mm[4*k+2] = m.z; mm[4*k+3] = m.w;
    }
    vv[EPT] = (base + EPT < BTOT) ? v[base + EPT] : 0.0f;

#pragma unroll
    for (int k = 0; k < EPT; ++k) {
        float m = (float)mm[k];
        dd[k] = rr[k] + kG * m * vv[k + 1] - vv[k];
    }

    // Phase 1: per-thread affine summaries (reverse scan, zero carry)
    float pv = 1.0f, sv = 0.0f, pa = 1.0f, sa = 0.0f;
#pragma unroll
    for (int k = EPT - 1; k >= 0; --k) {
        float m = (float)mm[k];
        float av = kG * m, aa = kGT * m;
        sv = rr[k] + av * sv;
        sa = dd[k] + aa * sa;
        pv *= av; pa *= aa;
    }

    // Phase 2: block-level suffix scan (Hillis-Steele on affine composition)
    __shared__ float lpv[TPB], lsv[TPB], lpa[TPB], lsa[TPB];
    lpv[j] = pv; lsv[j] = sv; lpa[j] = pa; lsa[j] = sa;
    __syncthreads();
#pragma unroll
    for (int d = 1; d < TPB; d <<= 1) {
        float cpv = lpv[j], csv = lsv[j], cpa = lpa[j], csa = lsa[j];
        bool has = (j + d) < TPB;
        float qpv = 1.0f, qsv = 0.0f, qpa = 1.0f, qsa = 0.0f;
        if (has) { qpv = lpv[j+d]; qsv = lsv[j+d]; qpa = lpa[j+d]; qsa = lsa[j+d]; }
        __syncthreads();
        if (has) {
            lpv[j] = cpv * qpv; lsv[j] = csv + cpv * qsv;
            lpa[j] = cpa * qpa; lsa[j] = csa + cpa * qsa;
        }
        __syncthreads();
    }
    float CinA = (j + 1 < TPB) ? lsa[j + 1] : 0.0f;  // chunk-local value at thread's right edge
    float QrA  = (j + 1 < TPB) ? lpa[j + 1] : 1.0f;  // decay product over threads to the right
    float chPv = lpv[0], chSv = lsv[0], chPa = lpa[0], chSa = lsa[0];

    // Phase 3: chunk-local A values + quadratic stats (A = L + q*C later)
    float x = CinA, ql = 1.0f;
    float s0 = 0, s1 = 0, s2 = 0, s3 = 0, s4 = 0;
#pragma unroll
    for (int k = EPT - 1; k >= 0; --k) {
        float m = (float)mm[k];
        float aa = kGT * m;
        x = dd[k] + aa * x;
        ql *= aa;
        float q = ql * QrA;
        s0 += x; s1 += q; s2 += x * x; s3 += x * q; s4 += q * q;
    }
    s0 = wave_red(s0); s1 = wave_red(s1); s2 = wave_red(s2);
    s3 = wave_red(s3); s4 = wave_red(s4);
    __shared__ float rb[4][5];
    int wid = j >> 6, ln = j & 63;
    if (ln == 0) { rb[wid][0]=s0; rb[wid][1]=s1; rb[wid][2]=s2; rb[wid][3]=s3; rb[wid][4]=s4; }
    __syncthreads();
    if (j == 0) {
        float t0=0,t1=0,t2=0,t3=0,t4=0;
        for (int w = 0; w < 4; ++w) { t0+=rb[w][0]; t1+=rb[w][1]; t2+=rb[w][2]; t3+=rb[w][3]; t4+=rb[w][4]; }
        ws[0*NCH+c] = chPv; ws[1*NCH+c] = chSv; ws[2*NCH+c] = chPa; ws[3*NCH+c] = chSa;
        ws[4*NCH+c] = t0;   ws[5*NCH+c] = t1;   ws[6*NCH+c] = t2;
        ws[7*NCH+c] = t3;   ws[8*NCH+c] = t4;
    }
}

__global__ __launch_bounds__(TPB) void k2_scan_chunks(float* __restrict__ ws) {
    const int j = threadIdx.x;
    const float* Pv  = ws + 0*NCH; const float* Sv  = ws + 1*NCH;
    const float* Pa  = ws + 2*NCH; const float* Sa  = ws + 3*NCH;
    const float* sL  = ws + 4*NCH; const float* sq  = ws + 5*NCH;
    const float* sL2 = ws + 6*NCH; const float* sLq = ws + 7*NCH;
    const float* sq2 = ws + 8*NCH;
    float* Cv_ = ws + 9*NCH; float* Ca_ = ws + 10*NCH;

    // Phase 1: compose this thread's CPT chunks, right to left
    float pv = 1.0f, sv = 0.0f, pa = 1.0f, sa = 0.0f;
#pragma unroll
    for (int i = j*CPT + CPT - 1; i >= j*CPT; --i) {
        sv = Sv[i] + Pv[i] * sv; pv = Pv[i] * pv;
        sa = Sa[i] + Pa[i] * sa; pa = Pa[i] * pa;
    }
    __shared__ float lpv[TPB], lsv[TPB], lpa[TPB], lsa[TPB];
    lpv[j] = pv; lsv[j] = sv; lpa[j] = pa; lsa[j] = sa;
    __syncthreads();
#pragma unroll
    for (int d = 1; d < TPB; d <<= 1) {
        float cpv = lpv[j], csv = lsv[j], cpa = lpa[j], csa = lsa[j];
        bool has = (j + d) < TPB;
        float qpv = 1.0f, qsv = 0.0f, qpa = 1.0f, qsa = 0.0f;
        if (has) { qpv = lpv[j+d]; qsv = lsv[j+d]; qpa = lpa[j+d]; qsa = lsa[j+d]; }
        __syncthreads();
        if (has) {
            lpv[j] = cpv * qpv; lsv[j] = csv + cpv * qsv;
            lpa[j] = cpa * qpa; lsa[j] = csa + cpa * qsa;
        }
        __syncthreads();
    }
    float Cv = (j + 1 < TPB) ? lsv[j + 1] : 0.0f;
    float Ca = (j + 1 < TPB) ? lsa[j + 1] : 0.0f;

    double dS = 0.0, dS2 = 0.0;
#pragma unroll
    for (int i = j*CPT + CPT - 1; i >= j*CPT; --i) {
        Cv_[i] = Cv; Ca_[i] = Ca;
        dS  += (double)(sL[i]  + Ca * sq[i]);
        dS2 += (double)(sL2[i] + 2.0f * Ca * sLq[i] + Ca * Ca * sq2[i]);
        Cv = Sv[i] + Pv[i] * Cv;
        Ca = Sa[i] + Pa[i] * Ca;
    }
#pragma unroll
    for (int o = 32; o > 0; o >>= 1) { dS += __shfl_down(dS, o); dS2 += __shfl_down(dS2, o); }
    __shared__ double r1[4], r2[4];
    int wid = j >> 6, ln = j & 63;
    if (ln == 0) { r1[wid] = dS; r2[wid] = dS2; }
    __syncthreads();
    if (j == 0) {
        double S  = r1[0] + r1[1] + r1[2] + r1[3];
        double S2 = r2[0] + r2[1] + r2[2] + r2[3];
        double n = (double)BTOT;
        double mean = S / n;
        double var = (S2 - S * mean) / (n - 1.0);   // unbiased (ddof=1)
        ws[11*NCH]     = (float)mean;
        ws[11*NCH + 1] = (float)(1.0 / sqrt(var));
    }
}

__global__ __launch_bounds__(TPB) void k3_finalize(
    const float* __restrict__ r, const float* __restrict__ v,
    const int* __restrict__ mk, const float* __restrict__ ws,
    float* __restrict__ outA, float* __restrict__ outV) {
    const int c = blockIdx.x;
    const int j = threadIdx.x;
    const int base = c * CS + j * EPT;

    float rr[EPT], vv[EPT + 1], dd[EPT];
    int mm[EPT];
    const float4* r4 = (const float4*)(r + base);
    const float4* v4 = (const float4*)(v + base);
    const int4*   m4 = (const int4*)(mk + base);
#pragma unroll
    for (int k = 0; k < EPT / 4; ++k) {
        float4 a = r4[k];
        rr[4*k] = a.x; rr[4*k+1] = a.y; rr[4*k+2] = a.z; rr[4*k+3] = a.w;
        float4 b = v4[k];
        vv[4*k] = b.x; vv[4*k+1] = b.y; vv[4*k+2] = b.z; vv[4*k+3] = b.w;
        int4 m = m4[k];
        mm[4*k] = m.x; mm[4*k+1] = m.y; mm[4*k+2] = m.z; mm[4*k+3] = m.w;
    }
    vv[EPT] = (base + EPT < BTOT) ? v[base + EPT] : 0.0f;
#pragma unroll
    for (int k = 0; k < EPT; ++k) {
        float m = (float)mm[k];
        dd[k] = rr[k] + kG * m * vv[k + 1] - vv[k];
    }

    float pv = 1.0f, sv = 0.0f, pa = 1.0f, sa = 0.0f;
#pragma unroll
    for (int k = EPT - 1; k >= 0; --k) {
        float m = (float)mm[k];
        float av = kG * m, aa = kGT * m;
        sv = rr[k] + av * sv;
        sa = dd[k] + aa * sa;
        pv *= av; pa *= aa;
    }
    __shared__ float lpv[TPB], lsv[TPB], lpa[TPB], lsa[TPB];
    lpv[j] = pv; lsv[j] = sv; lpa[j] = pa; lsa[j] = sa;
    __syncthreads();
#pragma unroll
    for (int d = 1; d < TPB; d <<= 1) {
        float cpv = lpv[j], csv = lsv[j], cpa = lpa[j], csa = lsa[j];
        bool has = (j + d) < TPB;
        float qpv = 1.0f, qsv = 0.0f, qpa = 1.0f, qsa = 0.0f;
        if (has) { qpv = lpv[j+d]; qsv = lsv[j+d]; qpa = lpa[j+d]; qsa = lsa[j+d]; }
        __syncthreads();
        if (has) {
            lpv[j] = cpv * qpv; lsv[j] = csv + cpv * qsv;
            lpa[j] = cpa * qpa; lsa[j] = csa + cpa * qsa;
        }
        __syncthreads();
    }
    float CinV = (j + 1 < TPB) ? lsv[j + 1] : 0.0f;
    float QrV  = (j + 1 < TPB) ? lpv[j + 1] : 1.0f;
    float CinA = (j + 1 < TPB) ? lsa[j + 1] : 0.0f;
    float QrA  = (j + 1 < TPB) ? lpa[j + 1] : 1.0f;

    float Ccv = ws[9*NCH + c];
    float Cca = ws[10*NCH + c];
    float mean = ws[11*NCH];
    float inv  = ws[11*NCH + 1];

    float xv = CinV + QrV * Ccv;   // true value at thread's right boundary
    float xa = CinA + QrA * Cca;
    float oA[EPT], oV[EPT];
#pragma unroll
    for (int k = EPT - 1; k >= 0; --k) {
        float m = (float)mm[k];
        xv = rr[k] + kG  * m * xv;
        xa = dd[k] + kGT * m * xa;
        oV[k] = xv;
        oA[k] = (xa - mean) * inv;
    }
    float4* a4 = (float4*)(outA + base);
    float4* w4 = (float4*)(outV + base);
#pragma unroll
    for (int k = 0; k < EPT / 4; ++k) {
        a4[k] = make_float4(oA[4*k], oA[4*k+1], oA[4*k+2], oA[4*k+3]);
        w4[k] = make_float4(oV[4*k], oV[4*k+1], oV[4*k+2], oV[4*k+3]);
    }
}

extern "C" void kernel_launch(void* const* d_in, const int* in_sizes, int n_in,
                              void* d_out, int out_size, void* d_ws, size_t ws_size,
                              hipStream_t stream) {
    const float* r  = (const float*)d_in[0];
    const float* v  = (const float*)d_in[1];
    const int*   mk = (const int*)d_in[2];
    float* out = (float*)d_out;
    float* ws  = (float*)d_ws;

    hipLaunchKernelGGL(k1_summarize, dim3(NCH), dim3(TPB), 0, stream, r, v, mk, ws);
    hipLaunchKernelGGL(k2_scan_chunks, dim3(1), dim3(TPB), 0, stream, ws);
    hipLaunchKernelGGL(k3_finalize, dim3(NCH), dim3(TPB), 0, stream,
                       r, v, mk, ws, out, out + BTOT);
}

// Round 3
// 115.282 us; speedup vs baseline: 1.0143x; 1.0143x over previous
//
#include <hip/hip_runtime.h>
#include <math.h>

// Fixed-size problem: B = 4194304
#define BTOT 4194304
#define TPB  256
#define EPT  16                 // elements per thread
#define CS   (TPB * EPT)        // 4096 elements per chunk/block
#define NCH  (BTOT / CS)        // 1024 chunks
#define CPT  (NCH / TPB)        // 4 chunks per thread in the chunk-scan

// ws layout (floats): 9 arrays of NCH chunk summaries
//  0:Pv 1:Sv 2:Pa 3:Sa 4:sL 5:sq 6:sL2 7:sLq 8:sq2

__constant__ const float kG  = 0.99f;
__constant__ const float kGT = 0.99f * 0.95f;

__device__ __forceinline__ float wave_redf(float x) {
#pragma unroll
    for (int o = 32; o > 0; o >>= 1) x += __shfl_down(x, o);
    return x;
}
__device__ __forceinline__ double wave_redd(double x) {
#pragma unroll
    for (int o = 32; o > 0; o >>= 1) x += __shfl_down(x, o);
    return x;
}

// Hillis-Steele suffix scan over the block on affine pairs (P,S) for both
// recurrences. Entry j ends as the composition of threads j..TPB-1.
__device__ __forceinline__ void block_suffix_scan(
    float pv, float sv, float pa, float sa,
    float* lpv, float* lsv, float* lpa, float* lsa, int j)
{
    lpv[j] = pv; lsv[j] = sv; lpa[j] = pa; lsa[j] = sa;
    __syncthreads();
#pragma unroll
    for (int d = 1; d < TPB; d <<= 1) {
        float cpv = lpv[j], csv = lsv[j], cpa = lpa[j], csa = lsa[j];
        bool has = (j + d) < TPB;
        float qpv = 1.0f, qsv = 0.0f, qpa = 1.0f, qsa = 0.0f;
        if (has) { qpv = lpv[j+d]; qsv = lsv[j+d]; qpa = lpa[j+d]; qsa = lsa[j+d]; }
        __syncthreads();
        if (has) {
            lpv[j] = cpv * qpv; lsv[j] = csv + cpv * qsv;
            lpa[j] = cpa * qpa; lsa[j] = csa + cpa * qsa;
        }
        __syncthreads();
    }
}

// ---------------- K1: per-chunk affine summaries + quadratic stats ---------
__global__ __launch_bounds__(TPB) void ppo_k1_summarize(
    const float* __restrict__ r, const float* __restrict__ v,
    const int* __restrict__ mk, float* __restrict__ ws) {
    const int c = blockIdx.x;
    const int j = threadIdx.x;
    const int base = c * CS + j * EPT;

    float rr[EPT], vv[EPT + 1], dd[EPT];
    int mm[EPT];
    const float4* r4 = (const float4*)(r + base);
    const float4* v4 = (const float4*)(v + base);
    const int4*   m4 = (const int4*)(mk + base);
#pragma unroll
    for (int k = 0; k < EPT / 4; ++k) {
        float4 a = r4[k];
        rr[4*k] = a.x; rr[4*k+1] = a.y; rr[4*k+2] = a.z; rr[4*k+3] = a.w;
        float4 b = v4[k];
        vv[4*k] = b.x; vv[4*k+1] = b.y; vv[4*k+2] = b.z; vv[4*k+3] = b.w;
        int4 m = m4[k];
        mm[4*k] = m.x; mm[4*k+1] = m.y; mm[4*k+2] = m.z; mm[4*k+3] = m.w;
    }
    vv[EPT] = (base + EPT < BTOT) ? v[base + EPT] : 0.0f;

#pragma unroll
    for (int k = 0; k < EPT; ++k) {
        float m = (float)mm[k];
        dd[k] = rr[k] + kG * m * vv[k + 1] - vv[k];
    }

    // per-thread affine summaries (reverse, zero carry)
    float pv = 1.0f, sv = 0.0f, pa = 1.0f, sa = 0.0f;
#pragma unroll
    for (int k = EPT - 1; k >= 0; --k) {
        float m = (float)mm[k];
        float av = kG * m, aa = kGT * m;
        sv = rr[k] + av * sv;
        sa = dd[k] + aa * sa;
        pv *= av; pa *= aa;
    }

    __shared__ float lpv[TPB], lsv[TPB], lpa[TPB], lsa[TPB];
    block_suffix_scan(pv, sv, pa, sa, lpv, lsv, lpa, lsa, j);

    float CinA = (j + 1 < TPB) ? lsa[j + 1] : 0.0f;
    float QrA  = (j + 1 < TPB) ? lpa[j + 1] : 1.0f;
    float chPv = lpv[0], chSv = lsv[0], chPa = lpa[0], chSa = lsa[0];

    // chunk-local A values + quadratic stats: A = L + q * C_chunk
    float x = CinA, ql = 1.0f;
    float s0 = 0, s1 = 0, s2 = 0, s3 = 0, s4 = 0;
#pragma unroll
    for (int k = EPT - 1; k >= 0; --k) {
        float m = (float)mm[k];
        float aa = kGT * m;
        x = dd[k] + aa * x;
        ql *= aa;
        float q = ql * QrA;
        s0 += x; s1 += q; s2 += x * x; s3 += x * q; s4 += q * q;
    }
    s0 = wave_redf(s0); s1 = wave_redf(s1); s2 = wave_redf(s2);
    s3 = wave_redf(s3); s4 = wave_redf(s4);
    __shared__ float rb[4][5];
    int wid = j >> 6, ln = j & 63;
    if (ln == 0) { rb[wid][0]=s0; rb[wid][1]=s1; rb[wid][2]=s2; rb[wid][3]=s3; rb[wid][4]=s4; }
    __syncthreads();
    if (j == 0) {
        float t0=0,t1=0,t2=0,t3=0,t4=0;
        for (int w = 0; w < 4; ++w) { t0+=rb[w][0]; t1+=rb[w][1]; t2+=rb[w][2]; t3+=rb[w][3]; t4+=rb[w][4]; }
        ws[0*NCH+c] = chPv; ws[1*NCH+c] = chSv; ws[2*NCH+c] = chPa; ws[3*NCH+c] = chSa;
        ws[4*NCH+c] = t0;   ws[5*NCH+c] = t1;   ws[6*NCH+c] = t2;
        ws[7*NCH+c] = t3;   ws[8*NCH+c] = t4;
    }
}

// ------- K2: every block redundantly scans chunk summaries, then finalizes
//         its own chunk (inputs re-read from L3). No grid sync needed. -----
__global__ __launch_bounds__(TPB) void ppo_k2_finalize(
    const float* __restrict__ r, const float* __restrict__ v,
    const int* __restrict__ mk, const float* __restrict__ ws,
    float* __restrict__ outA, float* __restrict__ outV)
{
    const int c = blockIdx.x;
    const int j = threadIdx.x;
    const int base = c * CS + j * EPT;

    __shared__ float lpv[TPB], lsv[TPB], lpa[TPB], lsa[TPB];
    __shared__ double rd[4][2];
    __shared__ float bcast[4];   // 0:carryV(into chunk c) 1:carryA 2:mean 3:inv_std

    // ---- redundant chunk-summary scan (identical in every block) ----
    {
        float cpv[CPT], csv[CPT], cpa[CPT], csa[CPT];
        {
            float4 t;
            t = *(const float4*)(ws + 0*NCH + 4*j); cpv[0]=t.x; cpv[1]=t.y; cpv[2]=t.z; cpv[3]=t.w;
            t = *(const float4*)(ws + 1*NCH + 4*j); csv[0]=t.x; csv[1]=t.y; csv[2]=t.z; csv[3]=t.w;
            t = *(const float4*)(ws + 2*NCH + 4*j); cpa[0]=t.x; cpa[1]=t.y; cpa[2]=t.z; cpa[3]=t.w;
            t = *(const float4*)(ws + 3*NCH + 4*j); csa[0]=t.x; csa[1]=t.y; csa[2]=t.z; csa[3]=t.w;
        }
        float gpv = 1.0f, gsv = 0.0f, gpa = 1.0f, gsa = 0.0f;
#pragma unroll
        for (int i = CPT - 1; i >= 0; --i) {
            gsv = csv[i] + cpv[i] * gsv; gpv = cpv[i] * gpv;
            gsa = csa[i] + cpa[i] * gsa; gpa = cpa[i] * gpa;
        }

        block_suffix_scan(gpv, gsv, gpa, gsa, lpv, lsv, lpa, lsa, j);

        float Cv = (j + 1 < TPB) ? lsv[j + 1] : 0.0f;
        float Ca = (j + 1 < TPB) ? lsa[j + 1] : 0.0f;

        float sLv[CPT], sqv[CPT], sL2v[CPT], sLqv[CPT], sq2v[CPT];
        {
            float4 t;
            t = *(const float4*)(ws + 4*NCH + 4*j); sLv[0]=t.x;  sLv[1]=t.y;  sLv[2]=t.z;  sLv[3]=t.w;
            t = *(const float4*)(ws + 5*NCH + 4*j); sqv[0]=t.x;  sqv[1]=t.y;  sqv[2]=t.z;  sqv[3]=t.w;
            t = *(const float4*)(ws + 6*NCH + 4*j); sL2v[0]=t.x; sL2v[1]=t.y; sL2v[2]=t.z; sL2v[3]=t.w;
            t = *(const float4*)(ws + 7*NCH + 4*j); sLqv[0]=t.x; sLqv[1]=t.y; sLqv[2]=t.z; sLqv[3]=t.w;
            t = *(const float4*)(ws + 8*NCH + 4*j); sq2v[0]=t.x; sq2v[1]=t.y; sq2v[2]=t.z; sq2v[3]=t.w;
        }
        double dS = 0.0, dS2 = 0.0;
#pragma unroll
        for (int i = CPT - 1; i >= 0; --i) {
            int g = 4*j + i;
            if (g == c) { bcast[0] = Cv; bcast[1] = Ca; }   // carry INTO our chunk
            dS  += (double)(sLv[i]  + Ca * sqv[i]);
            dS2 += (double)(sL2v[i] + 2.0f * Ca * sLqv[i] + Ca * Ca * sq2v[i]);
            Cv = csv[i] + cpv[i] * Cv;
            Ca = csa[i] + cpa[i] * Ca;
        }
        dS = wave_redd(dS); dS2 = wave_redd(dS2);
        int wid = j >> 6, ln = j & 63;
        if (ln == 0) { rd[wid][0] = dS; rd[wid][1] = dS2; }
        __syncthreads();
        if (j == 0) {
            double S  = rd[0][0] + rd[1][0] + rd[2][0] + rd[3][0];
            double S2 = rd[0][1] + rd[1][1] + rd[2][1] + rd[3][1];
            double n = (double)BTOT;
            double mean = S / n;
            double var = (S2 - S * mean) / (n - 1.0);   // ddof=1
            bcast[2] = (float)mean;
            bcast[3] = (float)(1.0 / sqrt(var));
        }
        __syncthreads();
    }

    // ---- finalize this block's chunk (inputs are L3-resident after K1) ----
    float rr[EPT], vv[EPT + 1], dd[EPT];
    int mm[EPT];
    const float4* r4 = (const float4*)(r + base);
    const float4* v4 = (const float4*)(v + base);
    const int4*   m4 = (const int4*)(mk + base);
#pragma unroll
    for (int k = 0; k < EPT / 4; ++k) {
        float4 a = r4[k];
        rr[4*k] = a.x; rr[4*k+1] = a.y; rr[4*k+2] = a.z; rr[4*k+3] = a.w;
        float4 b = v4[k];
        vv[4*k] = b.x; vv[4*k+1] = b.y; vv[4*k+2] = b.z; vv[4*k+3] = b.w;
        int4 m = m4[k];
        mm[4*k] = m.x; mm[4*k+1] = m.y; mm[4*k+2] = m.z; mm[4*k+3] = m.w;
    }
    vv[EPT] = (base + EPT < BTOT) ? v[base + EPT] : 0.0f;
#pragma unroll
    for (int k = 0; k < EPT; ++k) {
        float m = (float)mm[k];
        dd[k] = rr[k] + kG * m * vv[k + 1] - vv[k];
    }

    float pv = 1.0f, sv = 0.0f, pa = 1.0f, sa = 0.0f;
#pragma unroll
    for (int k = EPT - 1; k >= 0; --k) {
        float m = (float)mm[k];
        float av = kG * m, aa = kGT * m;
        sv = rr[k] + av * sv;
        sa = dd[k] + aa * sa;
        pv *= av; pa *= aa;
    }
    block_suffix_scan(pv, sv, pa, sa, lpv, lsv, lpa, lsa, j);

    float CinV = (j + 1 < TPB) ? lsv[j + 1] : 0.0f;
    float QrV  = (j + 1 < TPB) ? lpv[j + 1] : 1.0f;
    float CinA = (j + 1 < TPB) ? lsa[j + 1] : 0.0f;
    float QrA  = (j + 1 < TPB) ? lpa[j + 1] : 1.0f;

    const float Ccv  = bcast[0];
    const float Cca  = bcast[1];
    const float mean = bcast[2];
    const float inv  = bcast[3];

    float xv = CinV + QrV * Ccv;   // true value at this thread's right boundary
    float xa = CinA + QrA * Cca;
    float oA[EPT], oV[EPT];
#pragma unroll
    for (int k = EPT - 1; k >= 0; --k) {
        float m = (float)mm[k];
        xv = rr[k] + kG  * m * xv;
        xa = dd[k] + kGT * m * xa;
        oV[k] = xv;
        oA[k] = (xa - mean) * inv;
    }
    float4* a4 = (float4*)(outA + base);
    float4* w4 = (float4*)(outV + base);
#pragma unroll
    for (int k = 0; k < EPT / 4; ++k) {
        a4[k] = make_float4(oA[4*k], oA[4*k+1], oA[4*k+2], oA[4*k+3]);
        w4[k] = make_float4(oV[4*k], oV[4*k+1], oV[4*k+2], oV[4*k+3]);
    }
}

extern "C" void kernel_launch(void* const* d_in, const int* in_sizes, int n_in,
                              void* d_out, int out_size, void* d_ws, size_t ws_size,
                              hipStream_t stream) {
    const float* r  = (const float*)d_in[0];
    const float* v  = (const float*)d_in[1];
    const int*   mk = (const int*)d_in[2];
    float* outA = (float*)d_out;
    float* outV = outA + BTOT;
    float* ws   = (float*)d_ws;

    hipLaunchKernelGGL(ppo_k1_summarize, dim3(NCH), dim3(TPB), 0, stream,
                       r, v, mk, ws);
    hipLaunchKernelGGL(ppo_k2_finalize, dim3(NCH), dim3(TPB), 0, stream,
                       r, v, mk, ws, outA, outV);
}